// Round 1
// baseline (453.119 us; speedup 1.0000x reference)
//
#include <hip/hip_runtime.h>

#define IH 512
#define IW 512
#define OH 502
#define OW 502
#define NIMG 48
#define TOH 16
#define TOW 64
#define TIH (TOH + 10)     // 26
#define TIW (TOW + 10)     // 74
#define SXS (TIW + 2)      // 76 (float4-aligned row stride)
#define NTX 8              // ceil(502/64)
#define NTY 32             // ceil(502/16)
#define NBLK (NTX * NTY * NIMG)   // 12288
#define C1V 1.0e-4f
#define C2V 9.0e-4f

__global__ __launch_bounds__(256) void ssim_tile(const float* __restrict__ yt,
                                                 const float* __restrict__ yp,
                                                 float* __restrict__ partial) {
    __shared__ float sx[TIH][SXS];
    __shared__ float sy[TIH][SXS];
    __shared__ float t[5][TIH][TOW];   // 33280 B; first 8624 B aliased as raw-staging
    __shared__ float wred[4];

    const int tid = threadIdx.x;
    const int R0 = blockIdx.y * TOH;   // output-row origin
    const int C0 = blockIdx.x * TOW;   // output-col origin
    const size_t ib = (size_t)blockIdx.z * (IH * IW);

    // normalized gaussian (win=11, sigma=1.5), computed like the reference
    float g[11];
    {
        float s = 0.f;
#pragma unroll
        for (int i = 0; i < 11; i++) {
            float d = (float)(i - 5);
            float v = expf(-(d * d) * (1.f / 4.5f));
            g[i] = v; s += v;
        }
        float inv = 1.f / s;
#pragma unroll
        for (int i = 0; i < 11; i++) g[i] *= inv;
    }

    // ---- stage y_pred tile [TIH][TIW] (zero-guarded) ----
    for (int idx = tid; idx < TIH * TIW; idx += 256) {
        int i = idx / TIW, j = idx - i * TIW;
        int gr = R0 + i, gc = C0 + j;
        float v = 0.f;
        if (gr < IH && gc < IW) v = yp[ib + (size_t)gr * IW + gc];
        sy[i][j] = v;
    }
    // ---- stage y_true raw with +1 halo [TIH+2][TIW+2] into t-alias ----
    float* sraw = &t[0][0][0];
    const int RS = TIW + 3;            // 77 stride
    for (int idx = tid; idx < (TIH + 2) * (TIW + 2); idx += 256) {
        int i = idx / (TIW + 2), j = idx - i * (TIW + 2);
        int gr = R0 - 1 + i, gc = C0 - 1 + j;
        float v = 0.f;
        if (gr >= 0 && gr < IH && gc >= 0 && gc < IW) v = yt[ib + (size_t)gr * IW + gc];
        sraw[i * RS + j] = v;
    }
    __syncthreads();

    // ---- edge enhance: x = yt + lap(yt) = up+dn+lf+rt - 4*c  (SAME zero-pad) ----
    for (int idx = tid; idx < TIH * TIW; idx += 256) {
        int i = idx / TIW, j = idx - i * TIW;
        float c  = sraw[(i + 1) * RS + (j + 1)];
        float up = sraw[(i)     * RS + (j + 1)];
        float dn = sraw[(i + 2) * RS + (j + 1)];
        float lf = sraw[(i + 1) * RS + (j)];
        float rt = sraw[(i + 1) * RS + (j + 2)];
        sx[i][j] = up + dn + lf + rt - 4.f * c;
    }
    __syncthreads();   // sraw dead; t reusable

    // ---- W-pass: 5 blurred quantities -> t[5][TIH][TOW] ----
    for (int idx = tid; idx < TIH * 16; idx += 256) {   // 416 items
        int i = idx >> 4;
        int c0 = (idx & 15) << 2;
        float4 xa = *(const float4*)&sx[i][c0];
        float4 xb = *(const float4*)&sx[i][c0 + 4];
        float4 xc = *(const float4*)&sx[i][c0 + 8];
        float4 xd = *(const float4*)&sx[i][c0 + 12];
        float4 ya = *(const float4*)&sy[i][c0];
        float4 yb = *(const float4*)&sy[i][c0 + 4];
        float4 yc = *(const float4*)&sy[i][c0 + 8];
        float4 yd = *(const float4*)&sy[i][c0 + 12];
        float xv[16] = {xa.x, xa.y, xa.z, xa.w, xb.x, xb.y, xb.z, xb.w,
                        xc.x, xc.y, xc.z, xc.w, xd.x, xd.y, xd.z, xd.w};
        float yv[16] = {ya.x, ya.y, ya.z, ya.w, yb.x, yb.y, yb.z, yb.w,
                        yc.x, yc.y, yc.z, yc.w, yd.x, yd.y, yd.z, yd.w};
        float xx[14], yy[14], xy[14];
#pragma unroll
        for (int m = 0; m < 14; m++) { xx[m] = xv[m] * xv[m]; yy[m] = yv[m] * yv[m]; xy[m] = xv[m] * yv[m]; }
        float bx[4] = {0, 0, 0, 0}, by[4] = {0, 0, 0, 0};
        float bxx[4] = {0, 0, 0, 0}, byy[4] = {0, 0, 0, 0}, bxy[4] = {0, 0, 0, 0};
#pragma unroll
        for (int k = 0; k < 11; k++) {
            float w = g[k];
#pragma unroll
            for (int j = 0; j < 4; j++) {
                bx[j]  += w * xv[j + k];
                by[j]  += w * yv[j + k];
                bxx[j] += w * xx[j + k];
                byy[j] += w * yy[j + k];
                bxy[j] += w * xy[j + k];
            }
        }
        *(float4*)&t[0][i][c0] = make_float4(bx[0],  bx[1],  bx[2],  bx[3]);
        *(float4*)&t[1][i][c0] = make_float4(by[0],  by[1],  by[2],  by[3]);
        *(float4*)&t[2][i][c0] = make_float4(bxx[0], bxx[1], bxx[2], bxx[3]);
        *(float4*)&t[3][i][c0] = make_float4(byy[0], byy[1], byy[2], byy[3]);
        *(float4*)&t[4][i][c0] = make_float4(bxy[0], bxy[1], bxy[2], bxy[3]);
    }
    __syncthreads();

    // ---- H-pass + SSIM: 128 threads, each 4 cols x 2 rows; each t row read once ----
    float lsum = 0.f;
    if (tid < 128) {
        int c0 = (tid & 15) << 2;
        int r0 = (tid >> 4) << 1;    // 0..14
        float acc[2][5][4];
#pragma unroll
        for (int r = 0; r < 2; r++)
#pragma unroll
            for (int q = 0; q < 5; q++)
#pragma unroll
                for (int c = 0; c < 4; c++) acc[r][q][c] = 0.f;
#pragma unroll
        for (int i = 0; i < 12; i++) {
            float4 v[5];
#pragma unroll
            for (int q = 0; q < 5; q++) v[q] = *(const float4*)&t[q][r0 + i][c0];
#pragma unroll
            for (int r = 0; r < 2; r++) {
                const int kk = i - r;
                if (kk >= 0 && kk <= 10) {
                    float w = g[kk];
#pragma unroll
                    for (int q = 0; q < 5; q++) {
                        acc[r][q][0] += w * v[q].x;
                        acc[r][q][1] += w * v[q].y;
                        acc[r][q][2] += w * v[q].z;
                        acc[r][q][3] += w * v[q].w;
                    }
                }
            }
        }
#pragma unroll
        for (int r = 0; r < 2; r++) {
            int gr = R0 + r0 + r;
#pragma unroll
            for (int c = 0; c < 4; c++) {
                int gc = C0 + c0 + c;
                if (gr < OH && gc < OW) {
                    float mu1 = acc[r][0][c], mu2 = acc[r][1][c];
                    float exx = acc[r][2][c], eyy = acc[r][3][c], exy = acc[r][4][c];
                    float mu1s = mu1 * mu1, mu2s = mu2 * mu2, mu12 = mu1 * mu2;
                    float s1 = exx - mu1s, s2 = eyy - mu2s, s12 = exy - mu12;
                    float num = (2.f * mu12 + C1V) * (2.f * s12 + C2V);
                    float den = (mu1s + mu2s + C1V) * (s1 + s2 + C2V);
                    lsum += num / den;
                }
            }
        }
    }

    // ---- block reduce -> partial ----
#pragma unroll
    for (int off = 32; off > 0; off >>= 1) lsum += __shfl_down(lsum, off);
    if ((tid & 63) == 0) wred[tid >> 6] = lsum;
    __syncthreads();
    if (tid == 0) {
        int bid = blockIdx.x + NTX * (blockIdx.y + NTY * blockIdx.z);
        partial[bid] = wred[0] + wred[1] + wred[2] + wred[3];
    }
}

__global__ __launch_bounds__(256) void ssim_final(const float* __restrict__ partial,
                                                  float* __restrict__ out) {
    __shared__ double wred[4];
    double s = 0.0;
    for (int i = threadIdx.x; i < NBLK; i += 256) s += (double)partial[i];
#pragma unroll
    for (int off = 32; off > 0; off >>= 1) s += __shfl_down(s, off);
    if ((threadIdx.x & 63) == 0) wred[threadIdx.x >> 6] = s;
    __syncthreads();
    if (threadIdx.x == 0) {
        double tot = wred[0] + wred[1] + wred[2] + wred[3];
        out[0] = (float)(1.0 - tot / (double)((long long)OH * OW * NIMG));
    }
}

extern "C" void kernel_launch(void* const* d_in, const int* in_sizes, int n_in,
                              void* d_out, int out_size, void* d_ws, size_t ws_size,
                              hipStream_t stream) {
    const float* yt = (const float*)d_in[0];
    const float* yp = (const float*)d_in[1];
    float* out = (float*)d_out;
    float* partial = (float*)d_ws;   // NBLK floats = 48 KiB

    dim3 grid(NTX, NTY, NIMG);
    hipLaunchKernelGGL(ssim_tile, grid, dim3(256), 0, stream, yt, yp, partial);
    hipLaunchKernelGGL(ssim_final, dim3(1), dim3(256), 0, stream, partial, out);
}

// Round 2
// 128.166 us; speedup vs baseline: 3.5354x; 3.5354x over previous
//
#include <hip/hip_runtime.h>

#define IH 512
#define IW 512
#define OH 502
#define OW 502
#define NIMG 48
#define ROWS 32
#define NSTRIP 16                 // ceil(502/32)
#define NBLK (NSTRIP * NIMG)      // 768
#define BW 516                    // padded LDS row width (cols 512..515 zeroed)
#define C1V 1.0e-4f
#define C2V 9.0e-4f

// gaussian(win=11, sigma=1.5), normalized — matches reference to ~1e-7
__device__ __constant__ float G[11] = {
    0.00102838f, 0.00759876f, 0.03600078f, 0.10936070f, 0.21300554f,
    0.26601173f, 0.21300554f, 0.10936070f, 0.03600078f, 0.00759876f,
    0.00102838f};

// horizontal 11-tap blur of the 5 vertically-blurred quantities + SSIM.
// rowbuf slots 0..boff hold output rows obase..obase+boff (slot == row-obase).
__device__ __forceinline__ void hphase(float (*rowbuf)[5][BW], int boff, int tid,
                                       float& lsum) {
    __syncthreads();
    const int rb = tid >> 7;            // buffer row 0..3
    const int c0 = (tid & 127) << 2;    // output col base 0..508
    if (rb <= boff && c0 <= 500) {
        float out5[5][4];
#pragma unroll
        for (int q = 0; q < 5; q++) {
            const float* row = &rowbuf[rb][q][0];
            float4 f0 = *(const float4*)&row[c0];
            float4 f1 = *(const float4*)&row[c0 + 4];
            float4 f2 = *(const float4*)&row[c0 + 8];
            float4 f3 = *(const float4*)&row[c0 + 12];
            float v[14] = {f0.x, f0.y, f0.z, f0.w, f1.x, f1.y, f1.z, f1.w,
                           f2.x, f2.y, f2.z, f2.w, f3.x, f3.y};
#pragma unroll
            for (int j = 0; j < 4; j++) {
                float s = G[0] * v[j];
#pragma unroll
                for (int k = 1; k < 11; k++) s += G[k] * v[j + k];
                out5[q][j] = s;
            }
        }
#pragma unroll
        for (int j = 0; j < 4; j++) {
            if (c0 + j < OW) {
                float mu1 = out5[0][j], mu2 = out5[1][j];
                float exx = out5[2][j], eyy = out5[3][j], exy = out5[4][j];
                float mu1s = mu1 * mu1, mu2s = mu2 * mu2, mu12 = mu1 * mu2;
                float s1 = exx - mu1s, s2 = eyy - mu2s, s12 = exy - mu12;
                float num = (2.f * mu12 + C1V) * (2.f * s12 + C2V);
                float den = (mu1s + mu2s + C1V) * (s1 + s2 + C2V);
                lsum += num / den;
            }
        }
    }
    __syncthreads();
}

// process input rows ir = O0 + 11*OUTER + u, u=0..10 (ring slot math static).
template <int OUTER>
__device__ __forceinline__ void do11(float (&acc)[11][5], float& t_up, float& t_c,
                                     int O0, int oLast, int irLast, int c,
                                     const float* __restrict__ ytb,
                                     const float* __restrict__ ypb,
                                     float (*rowbuf)[5][BW], int tid, float& lsum) {
#pragma unroll
    for (int u = 0; u < 11; u++) {
        const int ir = O0 + OUTER * 11 + u;
        if (ir <= irLast) {                       // wave-uniform per block
            const float* rowp = ytb + ir * IW;
            float dn = (ir < IH - 1) ? rowp[IW + c] : 0.f;
            float lf = (c > 0) ? rowp[c - 1] : 0.f;
            float rt = (c < IW - 1) ? rowp[c + 1] : 0.f;
            float yv = ypb[ir * IW + c];
            // edge-enhance: x = yt + lap(yt), lap center = -5  => sum(nb) - 4*center
            float xv = t_up + dn + lf + rt - 4.f * t_c;
            float xx = xv * xv, yy2 = yv * yv, xy = xv * yv;
            // vertical blur: output-stationary ring accumulation
#pragma unroll
            for (int k = 0; k < 11; k++) {
                if (OUTER == 0 && k > u) continue;   // ramp guard (static)
                const int s = (u - k + 11) % 11;
                const float w = G[k];
                acc[s][0] += w * xv;
                acc[s][1] += w * yv;
                acc[s][2] += w * xx;
                acc[s][3] += w * yy2;
                acc[s][4] += w * xy;
            }
            if (OUTER != 0 || u == 10) {             // output row o = ir-10 done
                const int o = ir - 10;
                const int s = (u + 1) % 11;
                const int slot = (o - O0) & 3;
#pragma unroll
                for (int q = 0; q < 5; q++) {
                    rowbuf[slot][q][c] = acc[s][q];
                    acc[s][q] = 0.f;
                }
                const int rel = OUTER * 11 + u - 10; // == o - O0, compile-time
                if ((rel & 3) == 3 || rel == 21) {   // static phase-site filter
                    if ((rel & 3) == 3 || o == oLast)
                        hphase(rowbuf, (o - O0) & 3, tid, lsum);
                }
            }
            t_up = t_c;
            t_c = dn;
        }
    }
}

__global__ __launch_bounds__(512) void ssim_stream(const float* __restrict__ yt,
                                                   const float* __restrict__ yp,
                                                   float* __restrict__ partial) {
    __shared__ float rowbuf[4][5][BW];   // ~41.3 KB
    __shared__ float wred[8];

    const int tid = threadIdx.x;
    const int c = tid;                   // column 0..511
    const int strip = blockIdx.x;
    const int img = blockIdx.y;
    const int O0 = strip * ROWS;
    const int nrows = min(ROWS, OH - O0);
    const int oLast = O0 + nrows - 1;
    const int irLast = oLast + 10;
    const size_t ib = (size_t)img * (IH * IW);
    const float* ytb = yt + ib;
    const float* ypb = yp + ib;

    // zero the LDS pad columns (read by c0=500 threads, never written)
    if (tid < 80) {
        int slot = tid / 20, rem = tid % 20;
        rowbuf[slot][rem >> 2][512 + (rem & 3)] = 0.f;
    }

    float acc[11][5];
#pragma unroll
    for (int s = 0; s < 11; s++)
#pragma unroll
        for (int q = 0; q < 5; q++) acc[s][q] = 0.f;

    float t_up = (O0 > 0) ? ytb[(O0 - 1) * IW + c] : 0.f;
    float t_c = ytb[O0 * IW + c];
    float lsum = 0.f;

    do11<0>(acc, t_up, t_c, O0, oLast, irLast, c, ytb, ypb, rowbuf, tid, lsum);
    do11<1>(acc, t_up, t_c, O0, oLast, irLast, c, ytb, ypb, rowbuf, tid, lsum);
    do11<2>(acc, t_up, t_c, O0, oLast, irLast, c, ytb, ypb, rowbuf, tid, lsum);
    do11<3>(acc, t_up, t_c, O0, oLast, irLast, c, ytb, ypb, rowbuf, tid, lsum);

#pragma unroll
    for (int off = 32; off > 0; off >>= 1) lsum += __shfl_down(lsum, off);
    if ((tid & 63) == 0) wred[tid >> 6] = lsum;
    __syncthreads();
    if (tid == 0) {
        float s = 0.f;
#pragma unroll
        for (int w = 0; w < 8; w++) s += wred[w];
        partial[strip + NSTRIP * img] = s;
    }
}

__global__ __launch_bounds__(256) void ssim_final(const float* __restrict__ partial,
                                                  float* __restrict__ out) {
    __shared__ double wred[4];
    double s = 0.0;
    for (int i = threadIdx.x; i < NBLK; i += 256) s += (double)partial[i];
#pragma unroll
    for (int off = 32; off > 0; off >>= 1) s += __shfl_down(s, off);
    if ((threadIdx.x & 63) == 0) wred[threadIdx.x >> 6] = s;
    __syncthreads();
    if (threadIdx.x == 0) {
        double tot = wred[0] + wred[1] + wred[2] + wred[3];
        out[0] = (float)(1.0 - tot / (double)((long long)OH * OW * NIMG));
    }
}

extern "C" void kernel_launch(void* const* d_in, const int* in_sizes, int n_in,
                              void* d_out, int out_size, void* d_ws, size_t ws_size,
                              hipStream_t stream) {
    const float* yt = (const float*)d_in[0];
    const float* yp = (const float*)d_in[1];
    float* out = (float*)d_out;
    float* partial = (float*)d_ws;   // NBLK floats = 3 KB

    dim3 grid(NSTRIP, NIMG);
    hipLaunchKernelGGL(ssim_stream, grid, dim3(512), 0, stream, yt, yp, partial);
    hipLaunchKernelGGL(ssim_final, dim3(1), dim3(256), 0, stream, partial, out);
}

// Round 4
// 60.520 us; speedup vs baseline: 7.4872x; 2.1178x over previous
//
#include <hip/hip_runtime.h>

typedef _Float16 h2 __attribute__((ext_vector_type(2)));

#define IH 512
#define IW 512
#define OH 502
#define OW 502
#define NIMG 48
#define ROWS 32
#define NSTRIP 16                 // 16*32 = 512 >= 502
#define NBLK (NSTRIP * NIMG)      // 768
#define PADW 524                  // half2 words per rowbuf row (512 + halo pad)
#define C1V 1.0e-4f
#define C2V 9.0e-4f

// gaussian(win=11, sigma=1.5), normalized
constexpr float GFc[11] = {
    0.00102838f, 0.00759876f, 0.03600078f, 0.10936070f, 0.21300554f,
    0.26601173f, 0.21300554f, 0.10936070f, 0.03600078f, 0.00759876f,
    0.00102838f};

// cvt_pkrtz returns __fp16-vec; bit-cast to our _Float16-vec h2 (same layout)
static __device__ __forceinline__ h2 pkrtz(float a, float b) {
    return __builtin_bit_cast(h2, __builtin_amdgcn_cvt_pkrtz(a, b));
}

struct Pre {  // pipelined loads for one pair-step
    float a2, a3;   // yt col c,   rows ir+1, ir+2
    float b2, b3;   // yt col c-1, rows ir+1, ir+2
    float d2, d3;   // yt col c+1, rows ir+1, ir+2
    float e0, e1;   // yp col c,   rows ir,   ir+1
};

struct __align__(8) H22 { h2 x, y; };

// horizontal 11-tap blur (packed row-pair) + SSIM for 4 output rows
__device__ __forceinline__ void hphase(const h2 (*rbp)[5][PADW], int orow0,
                                       int tid, const h2 (&gh)[11], float& lsum) {
    const int rbrow = tid >> 8;          // 0..1 (pair-row within phase)
    const int c0 = (tid & 255) << 1;     // even output col base 0..510
    float ov[5][4];                      // [q][col*2 + row]
#pragma unroll
    for (int q = 0; q < 5; q++) {
        const h2* rowp = &rbp[rbrow][q][c0];
        h2 w[12];
#pragma unroll
        for (int u = 0; u < 6; u++) {
            H22 t = *(const H22*)(rowp + 2 * u);   // 8B-aligned LDS loads
            w[2 * u] = t.x; w[2 * u + 1] = t.y;
        }
        h2 s0 = gh[0] * w[0];
        h2 s1 = gh[0] * w[1];
#pragma unroll
        for (int k = 1; k < 11; k++) { s0 += gh[k] * w[k]; s1 += gh[k] * w[k + 1]; }
        ov[q][0] = (float)s0.x; ov[q][1] = (float)s0.y;
        ov[q][2] = (float)s1.x; ov[q][3] = (float)s1.y;
    }
    const int grb = orow0 + (rbrow << 1);
#pragma unroll
    for (int cl = 0; cl < 2; cl++) {
#pragma unroll
        for (int rw = 0; rw < 2; rw++) {
            const int gr = grb + rw, gc = c0 + cl;
            if (gr < OH && gc < OW) {
                const int e = cl * 2 + rw;
                float mu1 = ov[0][e], mu2 = ov[1][e];
                float exx = ov[2][e], eyy = ov[3][e], exy = ov[4][e];
                float mu1s = mu1 * mu1, mu2s = mu2 * mu2, mu12 = mu1 * mu2;
                float s1v = exx - mu1s, s2v = eyy - mu2s, s12 = exy - mu12;
                float num = (2.f * mu12 + C1V) * (2.f * s12 + C2V);
                float den = (mu1s + mu2s + C1V) * (s1v + s2v + C2V);
                lsum += num * __builtin_amdgcn_rcpf(den);
            }
        }
    }
}

// one pair-step: input rows ir = O0+2S, ir+1
template <int S>
__device__ __forceinline__ void stepf(
    float (&acc)[12][5], float& a0, float& a1, float& b1, float& d1, Pre& pre,
    const float* __restrict__ ytc, const float* __restrict__ ytcm,
    const float* __restrict__ ytcp, const float* __restrict__ ypc,
    int O0, bool cgt0, bool clt511,
    const h2 (&rp)[10], const h2 (&gh)[11], float g0s, float g10s,
    h2 (*rbuf)[2][5][PADW], int c, int tid, float& lsum) {
    const Pre cur = pre;
    // ---- issue next step's loads (latency hidden under this step's compute) ----
    if constexpr (S < 20) {
        int base = O0 + 2 * S;
        int rA = base + 3; rA = rA > (IH - 1) ? (IH - 1) : rA;
        int rB = base + 4; rB = rB > (IH - 1) ? (IH - 1) : rB;
        int rE = base + 2; rE = rE > (IH - 1) ? (IH - 1) : rE;
        pre.a2 = ytc[(size_t)rA * IW];  pre.a3 = ytc[(size_t)rB * IW];
        pre.b2 = ytcm[(size_t)rA * IW]; pre.b3 = ytcm[(size_t)rB * IW];
        pre.d2 = ytcp[(size_t)rA * IW]; pre.d3 = ytcp[(size_t)rB * IW];
        pre.e0 = ypc[(size_t)rE * IW];  pre.e1 = ypc[(size_t)rA * IW];
    }
    // ---- edge-enhance rows ir, ir+1 ----
    float lf0 = cgt0 ? b1 : 0.f;
    float rt0 = clt511 ? d1 : 0.f;
    float lf1 = cgt0 ? cur.b2 : 0.f;
    float rt1 = clt511 ? cur.d2 : 0.f;
    float xr0 = a0 + cur.a2 + lf0 + rt0 - 4.f * a1;
    float xr1 = a1 + cur.a3 + lf1 + rt1 - 4.f * cur.a2;
    float pr0[5] = {xr0, cur.e0, xr0 * xr0, cur.e0 * cur.e0, xr0 * cur.e0};
    float pr1[5] = {xr1, cur.e1, xr1 * xr1, cur.e1 * cur.e1, xr1 * cur.e1};
    h2 pk[5];
#pragma unroll
    for (int q = 0; q < 5; q++) pk[q] = pkrtz(pr0[q], pr1[q]);
    // ---- vertical ring: 2 taps per live output via fdot2 ----
    constexpr int RLO = (2 * S - 10 < 0) ? 0 : (2 * S - 10);
    constexpr int RHI = (2 * S + 1 > ROWS - 1) ? (ROWS - 1) : (2 * S + 1);
#pragma unroll
    for (int rel = RLO; rel <= RHI; ++rel) {
        const int k0 = 2 * S - rel;       // constant after unroll
        const int sl = rel % 12;
#pragma unroll
        for (int q = 0; q < 5; q++) {
            if (k0 == -1)
                acc[sl][q] = g0s * pr1[q];
            else if (k0 == 0)
                acc[sl][q] = __builtin_amdgcn_fdot2(rp[0], pk[q], 0.f, false);
            else if (k0 <= 9)
                acc[sl][q] = __builtin_amdgcn_fdot2(rp[k0], pk[q], acc[sl][q], false);
            else
                acc[sl][q] = fmaf(g10s, pr0[q], acc[sl][q]);
        }
    }
    // ---- carries ----
    a0 = cur.a2; a1 = cur.a3; b1 = cur.b3; d1 = cur.d3;
    // ---- emit completed row-pair (rel 2S-10, 2S-9) as packed half2 ----
    if constexpr (S >= 5) {
        constexpr int p2 = S - 5;
        constexpr int buf = (p2 >> 1) & 1;
        constexpr int sl2 = p2 & 1;
        constexpr int q0 = (2 * S - 10) % 12;
        constexpr int q1 = (2 * S - 9) % 12;
#pragma unroll
        for (int q = 0; q < 5; q++)
            rbuf[buf][sl2][q][c] = pkrtz(acc[q0][q], acc[q1][q]);
    }
    // ---- phase: single barrier (double-buffered rowbuf) ----
    if constexpr (S >= 6 && (S % 2) == 0) {
        __syncthreads();
        constexpr int buf = ((S - 5) >> 1) & 1;
        hphase(rbuf[buf], O0 + 2 * (S - 6), tid, gh, lsum);
    }
}

template <int S, typename... A>
__device__ __forceinline__ void run_steps(A&... a) {
    stepf<S>(a...);
    if constexpr (S < 20) run_steps<S + 1>(a...);
}

__global__ __launch_bounds__(512) void ssim_stream(const float* __restrict__ yt,
                                                   const float* __restrict__ yp,
                                                   float* __restrict__ partial) {
    __shared__ __align__(16) h2 rbuf[2][2][5][PADW];   // ~41.9 KB
    __shared__ float wred[8];

    const int tid = threadIdx.x;
    const int c = tid;
    const int strip = blockIdx.x;
    const int img = blockIdx.y;
    const int O0 = strip * ROWS;
    const size_t ib = (size_t)img * (IH * IW);
    const float* ytb = yt + ib;
    const float* ypb = yp + ib;

    const int cm = c > 0 ? c - 1 : 0;
    const int cp = c < (IW - 1) ? c + 1 : (IW - 1);
    const bool cgt0 = c > 0, clt511 = c < (IW - 1);
    const float* ytc = ytb + c;
    const float* ytcm = ytb + cm;
    const float* ytcp = ytb + cp;
    const float* ypc = ypb + c;

    // weights in registers (compile-time folded)
    h2 rp[10], gh[11];
#pragma unroll
    for (int k = 0; k < 10; k++) rp[k] = h2{(_Float16)GFc[k], (_Float16)GFc[k + 1]};
#pragma unroll
    for (int k = 0; k < 11; k++) gh[k] = h2{(_Float16)GFc[k], (_Float16)GFc[k]};
    const float g0s = GFc[0], g10s = GFc[10];

    // prologue: carries + first pair's loads
    float a0, a1, b1, d1;
    {
        int rm1 = O0 > 0 ? O0 - 1 : 0;
        float a0v = ytc[(size_t)rm1 * IW];
        a1 = ytc[(size_t)O0 * IW];
        b1 = ytcm[(size_t)O0 * IW];
        d1 = ytcp[(size_t)O0 * IW];
        a0 = (O0 > 0) ? a0v : 0.f;
    }
    Pre pre;
    {
        int r1 = O0 + 1, r2 = O0 + 2;
        pre.a2 = ytc[(size_t)r1 * IW];  pre.a3 = ytc[(size_t)r2 * IW];
        pre.b2 = ytcm[(size_t)r1 * IW]; pre.b3 = ytcm[(size_t)r2 * IW];
        pre.d2 = ytcp[(size_t)r1 * IW]; pre.d3 = ytcp[(size_t)r2 * IW];
        pre.e0 = ypc[(size_t)O0 * IW];  pre.e1 = ypc[(size_t)r1 * IW];
    }

    float acc[12][5];   // ring; every slot is init-on-first-tap
    float lsum = 0.f;

    run_steps<0>(acc, a0, a1, b1, d1, pre, ytc, ytcm, ytcp, ypc, O0, cgt0, clt511,
                 rp, gh, g0s, g10s, rbuf, c, tid, lsum);

#pragma unroll
    for (int off = 32; off > 0; off >>= 1) lsum += __shfl_down(lsum, off);
    if ((tid & 63) == 0) wred[tid >> 6] = lsum;
    __syncthreads();
    if (tid == 0) {
        float s = 0.f;
#pragma unroll
        for (int w = 0; w < 8; w++) s += wred[w];
        partial[strip + NSTRIP * img] = s;
    }
}

__global__ __launch_bounds__(256) void ssim_final(const float* __restrict__ partial,
                                                  float* __restrict__ out) {
    __shared__ double wred[4];
    double s = 0.0;
    for (int i = threadIdx.x; i < NBLK; i += 256) s += (double)partial[i];
#pragma unroll
    for (int off = 32; off > 0; off >>= 1) s += __shfl_down(s, off);
    if ((threadIdx.x & 63) == 0) wred[threadIdx.x >> 6] = s;
    __syncthreads();
    if (threadIdx.x == 0) {
        double tot = wred[0] + wred[1] + wred[2] + wred[3];
        out[0] = (float)(1.0 - tot / (double)((long long)OH * OW * NIMG));
    }
}

extern "C" void kernel_launch(void* const* d_in, const int* in_sizes, int n_in,
                              void* d_out, int out_size, void* d_ws, size_t ws_size,
                              hipStream_t stream) {
    const float* yt = (const float*)d_in[0];
    const float* yp = (const float*)d_in[1];
    float* out = (float*)d_out;
    float* partial = (float*)d_ws;   // NBLK floats = 3 KB

    dim3 grid(NSTRIP, NIMG);
    hipLaunchKernelGGL(ssim_stream, grid, dim3(512), 0, stream, yt, yp, partial);
    hipLaunchKernelGGL(ssim_final, dim3(1), dim3(256), 0, stream, partial, out);
}